// Round 7
// baseline (192.759 us; speedup 1.0000x reference)
//
#include <hip/hip_runtime.h>

#define NLAYER 7
#define IMGB 16384          // bytes per weight-layer image: A[n][k] fp8, 16B-chunk XOR-swizzled (key n&7)
#define WSCALE 16.0f        // weights stored x16 (e4m3 subnormal protection)

typedef __attribute__((ext_vector_type(2))) float float2v;
typedef __attribute__((ext_vector_type(4))) float float4v;
typedef __attribute__((ext_vector_type(4))) unsigned int uint4v;
typedef __attribute__((ext_vector_type(4))) int int4v;
typedef __attribute__((ext_vector_type(8))) int int8v;
typedef unsigned long long u64;

__device__ __forceinline__ float2v pk_fma(float2v a, float2v b, float2v c){
  return __builtin_elementwise_fma(a, b, c);
}
__device__ __forceinline__ float2v lo2(float4v v){ return (float2v){v[0], v[1]}; }
__device__ __forceinline__ float2v hi2(float4v v){ return (float2v){v[2], v[3]}; }

// pack 4 f32 -> 4 fp8 e4m3 bytes (ascending)
__device__ __forceinline__ unsigned pk4fp8(float v0, float v1, float v2, float v3){
  int w = __builtin_amdgcn_cvt_pk_fp8_f32(v0, v1, 0, false);
  w = __builtin_amdgcn_cvt_pk_fp8_f32(v2, v3, w, true);
  return (unsigned)w;
}
// MX-scaled MFMA, K=128, FMT=fp8 e4m3 both operands, scales = 1.0 (E8M0 0x7F)
__device__ __forceinline__ float4v mfma128(int8v a, int8v b){
  return __builtin_amdgcn_mfma_scale_f32_16x16x128_f8f6f4(
      a, b, (float4v){0.f,0.f,0.f,0.f}, 0, 0, 0, 0x7F7F7F7F, 0, 0x7F7F7F7F);
}
// P16 = 16*Phi(z) (cubic Taylor), gp16 = 16*gelu'(z)
__device__ __forceinline__ void act2(float2v z, float2v& P16, float2v& gp16){
  const float2v c1v  = {6.3830764862829235f, 6.3830764862829235f};
  const float2v c3v  = {-1.0638460810704874f, -1.0638460810704874f};
  const float2v c33v = {-3.1915382432114624f, -3.1915382432114624f};
  const float2v v8   = {8.f, 8.f};
  float2v z2 = z * z;
  float2v u  = pk_fma(z2, c3v, c1v);
  P16 = pk_fma(z, u, v8);
  float2v Pd = pk_fma(z2, c33v, c1v);
  gp16 = pk_fma(z, Pd, P16);
}

__device__ __forceinline__ void gl2lds16(const unsigned char* g, unsigned char* l){
  __builtin_amdgcn_global_load_lds((const __attribute__((address_space(1))) unsigned int*)g,
                                   (__attribute__((address_space(3))) unsigned int*)l,
                                   16, 0, 0);
}

// operand gather: 32 contiguous k-bytes from a 16B-swizzled row (key row&7).
// lp/hp pre-compensate the key-bit0 half-swap so k-order is preserved; all
// per-layer/tile displacements fold into ds_read immediate offsets.
__device__ __forceinline__ int8v ld_op16(const unsigned char* lp, const unsigned char* hp){
  int4v lo = *(const int4v*)lp;
  int4v hi = *(const int4v*)hp;
  return __builtin_shufflevector(lo, hi, 0, 1, 2, 3, 4, 5, 6, 7);
}

// ---- prep: Wh fp32 [side][term][L][k][n] -> fp8 image [net][L][n][16B chunk c4 ^ (n&7)], W*16 ----
__global__ __launch_bounds__(256)
void prep_weights(const float* __restrict__ lWh,
                  const float* __restrict__ rWh,
                  unsigned char* __restrict__ wbf)
{
  __shared__ __align__(16) unsigned char T[IMGB];
  const int b = blockIdx.x;               // net*7 + L
  const int net = b / NLAYER, L = b % NLAYER;
  const int side = net >> 1, term = net & 1;
  const float* src = (side ? rWh : lWh) + (size_t)((term*NLAYER + L)*128)*128;
  const int t = threadIdx.x;
  {
    const int k = t >> 1, n0 = (t & 1)*64;
    const float* row = src + k*128 + n0;
    #pragma unroll
    for (int c4 = 0; c4 < 4; ++c4){
      float4v f0 = *(const float4v*)(row + c4*16);
      float4v f1 = *(const float4v*)(row + c4*16 + 4);
      float4v f2 = *(const float4v*)(row + c4*16 + 8);
      float4v f3 = *(const float4v*)(row + c4*16 + 12);
      uint4v wv = { pk4fp8(f0[0]*WSCALE, f0[1]*WSCALE, f0[2]*WSCALE, f0[3]*WSCALE),
                    pk4fp8(f1[0]*WSCALE, f1[1]*WSCALE, f1[2]*WSCALE, f1[3]*WSCALE),
                    pk4fp8(f2[0]*WSCALE, f2[1]*WSCALE, f2[2]*WSCALE, f2[3]*WSCALE),
                    pk4fp8(f3[0]*WSCALE, f3[1]*WSCALE, f3[2]*WSCALE, f3[3]*WSCALE) };
      *(uint4v*)&T[k*128 + n0 + c4*16] = wv;
    }
  }
  __syncthreads();
  {
    const int n = t >> 1, c0 = (t & 1)*8;
    const int sw7 = n & 7;
    unsigned char* dst = wbf + ((size_t)b << 14) + n*128;
    #pragma unroll
    for (int c = 0; c < 8; ++c){
      const int c64 = c0 + c;                 // u64 chunk 0..15, k in [c64*8, c64*8+8)
      const int kc = c64*8;
      u64 v = 0;
      #pragma unroll
      for (int j = 0; j < 8; ++j)
        v |= (u64)T[(kc + j)*128 + n] << (8*j);
      *(u64*)(dst + (((c64 >> 1) ^ sw7)*16) + (c64 & 1)*8) = v;
    }
  }
}

// WAVE-AUTONOMOUS structure: each wave owns 16 elements end-to-end (all 128 n,
// 16 MFMAs/layer). sH is wave-PRIVATE (4KB/wave, in-place, own-wave lgkm order):
// no cross-wave activation coupling. Input layer computes b0/b1 fragments directly
// in registers (its output IS the lane's next B-fragment); final layer folds the
// Wo-reduce from acc registers (shfl_xor over the 4 q-lanes). The ONLY shared
// resource is the double-buffered sW image -> ONE barrier per layer (7/eval).
// 256 thr / 4 waves / 64 elems; grid (256,2)=512 = 2 blocks/CU; LDS 48KB.
__global__ __launch_bounds__(256)
__attribute__((amdgpu_waves_per_eu(2, 2)))   // exactly 2 waves/EU -> 256-VGPR budget, no spill squeeze
void sympl_main(const float* __restrict__ X,
                const float* __restrict__ lW0, const float* __restrict__ lb0,
                const float* __restrict__ lbh, const float* __restrict__ lWo,
                const float* __restrict__ rW0, const float* __restrict__ rb0,
                const float* __restrict__ rbh, const float* __restrict__ rWo,
                const int* __restrict__ lidx, const int* __restrict__ ridx,
                const unsigned char* __restrict__ wbf,
                float* __restrict__ out)
{
  __shared__ __align__(16) unsigned char sWb[2*IMGB];   // weight double-buffer
  __shared__ __align__(16) unsigned char sH[4*4096];    // per-wave: H 2KB + D 2KB, in-place

  const int tid  = threadIdx.x;
  const int lane = tid & 63;
  const int w    = tid >> 6;        // wave 0..3
  const int m0   = lane & 15;       // element within wave / MFMA col
  const int q    = lane >> 4;       // k-quarter / n-subcolumn
  const int q4   = q * 4;
  const int m06  = m0 & 6;
  const int m07  = m0 & 7;
  const int col  = blockIdx.y;
  const int e    = blockIdx.x*64 + w*16 + m0;   // global element (4 q-lane copies)

  const int lt = (lidx[0] == col) ? 0 : 1;
  const int rt = (ridx[0] == col) ? 0 : 1;

  float qv = X[e*4 + col];
  float pv = X[e*4 + 2 + col];

  const float dt = 0.1f;
  const float C0 = 0.6756035959798289f, C1 = -0.17560359597982883f;
  const float D0 = 1.3512071919596578f, D1 = -1.7024143839193153f;
  // fold 1/(16*4^7) = 1/262144 (final S_d scale) into the step coefficients
  const float is = 1.0f / 262144.0f;
  const float coefs[7] = { C0*dt*is, -D0*dt*is, C1*dt*is, -D1*dt*is,
                           C1*dt*is, -D0*dt*is, C0*dt*is };

  const float2v inv256v = {1.f/256.f, 1.f/256.f};
  const float2v inv64v  = {1.f/64.f, 1.f/64.f};

  // hoisted LDS addresses (all per-layer/tile displacements = immediates)
  const int lo16 = (m0 & 1) * 16;
  const int opo  = ((2*q) ^ m06) * 16;
  const unsigned char* pAlo = sWb + m0*128 + opo + lo16;        // + bufo + I*2048
  const unsigned char* pAhi = sWb + m0*128 + opo + 16 - lo16;
  unsigned char* pHw = sH + w*4096 + m0*128;                    // own H row; D at +2048
  const unsigned char* pBlo = pHw + opo + lo16;                 // own B-fragment read
  const unsigned char* pBhi = pHw + opo + 16 - lo16;

  // prologue: stage sW buffer 0 for ev=0 (right net, term rt, L=0)
  {
    const unsigned char* src = wbf + (size_t)(2 + rt)*NLAYER*IMGB;
    #pragma unroll
    for (int it = 0; it < 4; ++it){
      int o = (it*256 + tid) * 16;
      gl2lds16(src + o, sWb + o);
    }
  }
  __syncthreads();

  for (int ev = 0; ev < 7; ++ev){
    const bool isT = !(ev & 1);
    const int  evp = ev & 1;          // sW parity generator: par(L) = evp ^ (L&1)
    const int  term = isT ? rt : lt;
    const float* W0p = (isT ? rW0 : lW0) + term*128;
    const float* b0p = (isT ? rb0 : lb0) + term*128;
    const float* bhp = (isT ? rbh : lbh) + term*NLAYER*128;
    const float* Wop = (isT ? rWo : lWo) + term*128;
    const unsigned char* wimg = wbf + (size_t)(((isT ? 2 : 0) + term)*NLAYER)*IMGB;
    const int tnx = (ev & 1) ? rt : lt;
    const unsigned char* wimg_nx = wbf + (size_t)((((ev & 1) ? 2 : 0) + tnx)*NLAYER)*IMGB;

    // ---- input layer: b0 = S_h frag, b1 = S_d frag, DIRECTLY in registers.
    // Lane (m0,q) computes element m0's features [32q, 32q+32) = exactly its own
    // B-fragment for the first hidden MFMA. No LDS, no barrier.
    int8v b0, b1;
    {
      const float x = isT ? pv : qv;
      const float2v xv = {x, x};
      const float* Wq = W0p + q*32;
      const float* Bq = b0p + q*32;
      unsigned hwv[8], dwv[8];
      #pragma unroll
      for (int j = 0; j < 8; ++j){
        float4v wv4 = *(const float4v*)(Wq + j*4);
        float4v bb4 = *(const float4v*)(Bq + j*4);
        float2v zlo = pk_fma(xv, lo2(wv4), lo2(bb4));
        float2v zhi = pk_fma(xv, hi2(wv4), hi2(bb4));
        float2v Pl, gl, Ph, gh;
        act2(zlo, Pl, gl);
        act2(zhi, Ph, gh);
        float2v hl = zlo * Pl, hh = zhi * Ph;
        float2v dl = gl * lo2(wv4), dh = gh * hi2(wv4);
        hwv[j] = pk4fp8(hl[0], hl[1], hh[0], hh[1]);
        dwv[j] = pk4fp8(dl[0], dl[1], dh[0], dh[1]);
      }
      b0 = (int8v){(int)hwv[0],(int)hwv[1],(int)hwv[2],(int)hwv[3],
                   (int)hwv[4],(int)hwv[5],(int)hwv[6],(int)hwv[7]};
      b1 = (int8v){(int)dwv[0],(int)dwv[1],(int)dwv[2],(int)dwv[3],
                   (int)dwv[4],(int)dwv[5],(int)dwv[6],(int)dwv[7]};
    }

    float2v sv = {0.f, 0.f};

    // ---- hidden layers: per wave 8 tiles x 2 streams; MFMA_I and EPI_I
    // interleave within the wave (scheduler); ONE barrier/layer for sW only.
    #pragma unroll
    for (int L = 0; L < NLAYER; ++L){
      const int par  = (L & 1) ? (evp ^ 1) : evp;   // sW read buffer
      const int bufo = par ? IMGB : 0;
      const bool last = (L == NLAYER-1);

      // bias (and Wo at last layer): hoisted broadcast loads
      const float* bias = bhp + L*128 + q4;
      float4v bvv[8];
      #pragma unroll
      for (int I = 0; I < 8; ++I) bvv[I] = *(const float4v*)(bias + I*16);
      float4v wov[8];
      if (last){
        #pragma unroll
        for (int I = 0; I < 8; ++I) wov[I] = *(const float4v*)(Wop + I*16 + q4);
      }

      // stage NEXT weight image into the other sW buffer (drains at this barrier)
      if (!(ev == 6 && L == 6)){
        const unsigned char* nsrc = (L < 6) ? (wimg + (size_t)(L+1)*IMGB) : wimg_nx;
        unsigned char* dW = sWb + (bufo ^ IMGB);
        #pragma unroll
        for (int it = 0; it < 4; ++it){
          int o = (it*256 + tid) * 16;
          gl2lds16(nsrc + o, dW + o);
        }
      }

      const unsigned char* pAl = pAlo + bufo;
      const unsigned char* pAh = pAhi + bufo;
      #pragma unroll
      for (int I = 0; I < 8; ++I){
        int8v a = ld_op16(pAl + I*2048, pAh + I*2048);
        float4v aH = mfma128(a, b0);
        float4v aD = mfma128(a, b1);
        // epilogue for tile I: z = accH/256 + b; S_h' = z*P16; S_d' = gp16*(accD/64)
        float2v za = pk_fma(lo2(aH), inv256v, lo2(bvv[I]));
        float2v zb = pk_fma(hi2(aH), inv256v, hi2(bvv[I]));
        float2v ta = lo2(aD) * inv64v;
        float2v tb = hi2(aD) * inv64v;
        float2v Pa, ga, Pb, gb;
        act2(za, Pa, ga);
        act2(zb, Pb, gb);
        float2v da = ga * ta, db = gb * tb;
        if (!last){
          float2v ha = za * Pa, hb = zb * Pb;
          const int eo = (I ^ m07)*16 + q4;
          *(unsigned*)(pHw + eo)        = pk4fp8(ha[0], ha[1], hb[0], hb[1]);
          *(unsigned*)(pHw + 2048 + eo) = pk4fp8(da[0], da[1], db[0], db[1]);
        } else {
          // fold Wo-reduce directly from registers (features I*16+q4..+4)
          sv = pk_fma(da, lo2(wov[I]), sv);
          sv = pk_fma(db, hi2(wov[I]), sv);
        }
      }

      // next layer's B-fragments from OWN sH (ordered vs own writes by lgkm)
      if (!last){
        b0 = ld_op16(pBlo, pBhi);
        b1 = ld_op16(pBlo + 2048, pBhi + 2048);
      }

      // sW rotation barrier: own A-reads retired (lgkm) + own staging DMAs done
      // (vmcnt) before release; after release all waves' staging is complete.
      asm volatile("s_waitcnt vmcnt(0) lgkmcnt(0)" ::: "memory");
      __builtin_amdgcn_s_barrier();
      asm volatile("" ::: "memory");
    }

    // ---- reduce: s = S_d7 . Wo over the 4 q-lanes of this element ----
    {
      float s = sv[0] + sv[1];
      s += __shfl_xor(s, 16);
      s += __shfl_xor(s, 32);
      if (isT) qv += coefs[ev] * s;
      else     pv += coefs[ev] * s;
    }
  }

  if (q == 0){
    out[e*4 + col]     = qv;
    out[e*4 + 2 + col] = pv;
  }
}

extern "C" void kernel_launch(void* const* d_in, const int* in_sizes, int n_in,
                              void* d_out, int out_size, void* d_ws, size_t ws_size,
                              hipStream_t stream)
{
  const float* X   = (const float*)d_in[0];
  const float* lW0 = (const float*)d_in[1];
  const float* lb0 = (const float*)d_in[2];
  const float* lWh = (const float*)d_in[3];
  const float* lbh = (const float*)d_in[4];
  const float* lWo = (const float*)d_in[5];
  const float* rW0 = (const float*)d_in[7];
  const float* rb0 = (const float*)d_in[8];
  const float* rWh = (const float*)d_in[9];
  const float* rbh = (const float*)d_in[10];
  const float* rWo = (const float*)d_in[11];
  const int*   li  = (const int*)d_in[13];
  const int*   ri  = (const int*)d_in[14];
  unsigned char* wbf = (unsigned char*)d_ws;   // 4*7*16384 B = 458752 B
  float* out = (float*)d_out;
  const int B = in_sizes[0] / 4;

  hipLaunchKernelGGL(prep_weights, dim3(4*NLAYER), dim3(256), 0, stream,
                     lWh, rWh, wbf);
  hipLaunchKernelGGL(sympl_main, dim3(B/64, 2), dim3(256), 0, stream,
                     X, lW0, lb0, lbh, lWo, rW0, rb0, rbh, rWo, li, ri, wbf, out);
}

// Round 8
// 186.442 us; speedup vs baseline: 1.0339x; 1.0339x over previous
//
#include <hip/hip_runtime.h>

#define NLAYER 7
#define IMGB 16384          // bytes per weight-layer image: A[n][k] fp8, 16B-chunk XOR-swizzled (key n&7)
#define WSCALE 16.0f        // weights stored x16 (e4m3 subnormal protection)

typedef __attribute__((ext_vector_type(2))) float float2v;
typedef __attribute__((ext_vector_type(4))) float float4v;
typedef __attribute__((ext_vector_type(4))) unsigned int uint4v;
typedef __attribute__((ext_vector_type(4))) int int4v;
typedef __attribute__((ext_vector_type(8))) int int8v;
typedef unsigned long long u64;

__device__ __forceinline__ float2v pk_fma(float2v a, float2v b, float2v c){
  return __builtin_elementwise_fma(a, b, c);
}
__device__ __forceinline__ float2v lo2(float4v v){ return (float2v){v[0], v[1]}; }
__device__ __forceinline__ float2v hi2(float4v v){ return (float2v){v[2], v[3]}; }

// pack 4 f32 -> 4 fp8 e4m3 bytes (ascending)
__device__ __forceinline__ unsigned pk4fp8(float v0, float v1, float v2, float v3){
  int w = __builtin_amdgcn_cvt_pk_fp8_f32(v0, v1, 0, false);
  w = __builtin_amdgcn_cvt_pk_fp8_f32(v2, v3, w, true);
  return (unsigned)w;
}
// MX-scaled MFMA, K=128, FMT=fp8 e4m3 both operands, scales = 1.0 (E8M0 0x7F)
__device__ __forceinline__ float4v mfma128(int8v a, int8v b){
  return __builtin_amdgcn_mfma_scale_f32_16x16x128_f8f6f4(
      a, b, (float4v){0.f,0.f,0.f,0.f}, 0, 0, 0, 0x7F7F7F7F, 0, 0x7F7F7F7F);
}
// P16 = 16*Phi(z) (cubic Taylor), gp16 = 16*gelu'(z)
__device__ __forceinline__ void act2(float2v z, float2v& P16, float2v& gp16){
  const float2v c1v  = {6.3830764862829235f, 6.3830764862829235f};
  const float2v c3v  = {-1.0638460810704874f, -1.0638460810704874f};
  const float2v c33v = {-3.1915382432114624f, -3.1915382432114624f};
  const float2v v8   = {8.f, 8.f};
  float2v z2 = z * z;
  float2v u  = pk_fma(z2, c3v, c1v);
  P16 = pk_fma(z, u, v8);
  float2v Pd = pk_fma(z2, c33v, c1v);
  gp16 = pk_fma(z, Pd, P16);
}

__device__ __forceinline__ void gl2lds16(const unsigned char* g, unsigned char* l){
  __builtin_amdgcn_global_load_lds((const __attribute__((address_space(1))) unsigned int*)g,
                                   (__attribute__((address_space(3))) unsigned int*)l,
                                   16, 0, 0);
}

// operand gather: 32 contiguous k-bytes from a 16B-swizzled row (key row&7).
// lp/hp pre-compensate the key-bit0 half-swap so k-order is preserved; all
// per-layer/tile displacements fold into ds_read immediate offsets.
__device__ __forceinline__ int8v ld_op16(const unsigned char* lp, const unsigned char* hp){
  int4v lo = *(const int4v*)(lp);
  int4v hi = *(const int4v*)(hp);
  return __builtin_shufflevector(lo, hi, 0, 1, 2, 3, 4, 5, 6, 7);
}

// ---- prep: Wh fp32 [side][term][L][k][n] -> fp8 image [net][L][n][16B chunk c4 ^ (n&7)], W*16 ----
__global__ __launch_bounds__(256)
void prep_weights(const float* __restrict__ lWh,
                  const float* __restrict__ rWh,
                  unsigned char* __restrict__ wbf)
{
  __shared__ __align__(16) unsigned char T[IMGB];
  const int b = blockIdx.x;               // net*7 + L
  const int net = b / NLAYER, L = b % NLAYER;
  const int side = net >> 1, term = net & 1;
  const float* src = (side ? rWh : lWh) + (size_t)((term*NLAYER + L)*128)*128;
  const int t = threadIdx.x;
  {
    const int k = t >> 1, n0 = (t & 1)*64;
    const float* row = src + k*128 + n0;
    #pragma unroll
    for (int c4 = 0; c4 < 4; ++c4){
      float4v f0 = *(const float4v*)(row + c4*16);
      float4v f1 = *(const float4v*)(row + c4*16 + 4);
      float4v f2 = *(const float4v*)(row + c4*16 + 8);
      float4v f3 = *(const float4v*)(row + c4*16 + 12);
      uint4v wv = { pk4fp8(f0[0]*WSCALE, f0[1]*WSCALE, f0[2]*WSCALE, f0[3]*WSCALE),
                    pk4fp8(f1[0]*WSCALE, f1[1]*WSCALE, f1[2]*WSCALE, f1[3]*WSCALE),
                    pk4fp8(f2[0]*WSCALE, f2[1]*WSCALE, f2[2]*WSCALE, f2[3]*WSCALE),
                    pk4fp8(f3[0]*WSCALE, f3[1]*WSCALE, f3[2]*WSCALE, f3[3]*WSCALE) };
      *(uint4v*)&T[k*128 + n0 + c4*16] = wv;
    }
  }
  __syncthreads();
  {
    const int n = t >> 1, c0 = (t & 1)*8;
    const int sw7 = n & 7;
    unsigned char* dst = wbf + ((size_t)b << 14) + n*128;
    #pragma unroll
    for (int c = 0; c < 8; ++c){
      const int c64 = c0 + c;                 // u64 chunk 0..15, k in [c64*8, c64*8+8)
      const int kc = c64*8;
      u64 v = 0;
      #pragma unroll
      for (int j = 0; j < 8; ++j)
        v |= (u64)T[(kc + j)*128 + n] << (8*j);
      *(u64*)(dst + (((c64 >> 1) ^ sw7)*16) + (c64 & 1)*8) = v;
    }
  }
}

// R6 structure (512 thr / 8 waves / 64 elems / ping-pong sH / ONE barrier per layer)
// + R7's register endpoints:
//  - element ownership e = g2*16 + m0 per thread (8 dup threads: q x ih)
//  - input layer computed in registers per wave (own B-fragment) -> no layer-0
//    LDS phase, no layer-0 barrier (7 barriers/eval)
//  - last layer folds Wo into registers from unquantized acc; cross-ih exchange
//    via 512B sRed scratch ordered by the existing end-of-layer barrier.
// LDS = 32K (sW dbuf) + 32K (sH ping-pong) + 512B (sRed) -> 2 blocks/CU.
__global__ __launch_bounds__(512)
__attribute__((amdgpu_waves_per_eu(4, 4)))
void sympl_main(const float* __restrict__ X,
                const float* __restrict__ lW0, const float* __restrict__ lb0,
                const float* __restrict__ lbh, const float* __restrict__ lWo,
                const float* __restrict__ rW0, const float* __restrict__ rb0,
                const float* __restrict__ rbh, const float* __restrict__ rWo,
                const int* __restrict__ lidx, const int* __restrict__ ridx,
                const unsigned char* __restrict__ wbf,
                float* __restrict__ out)
{
  __shared__ __align__(16) unsigned char sWb[2*IMGB];   // weight double-buffer
  __shared__ __align__(16) unsigned char sH[2*16384];   // parity P: H rows at P+e*128, D at P+8192+e*128
  __shared__ float sRed[2][64];                         // last-layer partial sums (ih x element)

  const int tid  = threadIdx.x;
  const int lane = tid & 63;
  const int w    = tid >> 6;        // wave 0..7
  const int m0   = lane & 15;
  const int q    = lane >> 4;
  const int q4   = q * 4;
  const int g2   = w & 3;           // element group (16 elems each)
  const int ih   = w >> 2;          // n_out half (tiles ih*4 .. ih*4+3)
  const int m06  = m0 & 6;
  const int m07  = m0 & 7;
  const int col  = blockIdx.y;
  const int le   = g2*16 + m0;                  // element within block
  const int e    = blockIdx.x*64 + le;          // global element (8 dup threads)

  const int lt = (lidx[0] == col) ? 0 : 1;
  const int rt = (ridx[0] == col) ? 0 : 1;

  float qv = X[e*4 + col];
  float pv = X[e*4 + 2 + col];

  const float dt = 0.1f;
  const float C0 = 0.6756035959798289f, C1 = -0.17560359597982883f;
  const float D0 = 1.3512071919596578f, D1 = -1.7024143839193153f;
  // fold 1/(16*4^7) = 1/262144 (final S_d scale) into the step coefficients
  const float is = 1.0f / 262144.0f;
  const float coefs[7] = { C0*dt*is, -D0*dt*is, C1*dt*is, -D1*dt*is,
                           C1*dt*is, -D0*dt*is, C0*dt*is };

  const float2v inv256v = {1.f/256.f, 1.f/256.f};
  const float2v inv64v  = {1.f/64.f, 1.f/64.f};

  // hoisted, loop-invariant LDS addresses; parity (0/16384), stream (+8192) and
  // tile (i*2048) displacements fold into ds immediate offsets after full unroll.
  const int lo16 = (m0 & 1) * 16;
  const int opo  = ((2*q) ^ m06) * 16;
  const unsigned char* pBlo = sH + le*128 + opo + lo16;         // B-fragment read base
  const unsigned char* pBhi = sH + le*128 + opo + 16 - lo16;
  const unsigned char* pAlo = sWb + (ih*64 + m0)*128 + opo + lo16;   // + bufo + i*2048
  const unsigned char* pAhi = sWb + (ih*64 + m0)*128 + opo + 16 - lo16;
  unsigned char* pHe = sH + le*128;                             // epilogue write base
  unsigned char* pE0 = pHe + ((ih*4 + 0) ^ m07)*16 + q4;
  unsigned char* pE1 = pHe + ((ih*4 + 1) ^ m07)*16 + q4;
  unsigned char* pE2 = pHe + ((ih*4 + 2) ^ m07)*16 + q4;
  unsigned char* pE3 = pHe + ((ih*4 + 3) ^ m07)*16 + q4;

  // prologue: stage sW buffer 0 for ev=0 (right net, term rt, L=0)
  {
    const unsigned char* src = wbf + (size_t)(2 + rt)*NLAYER*IMGB;
    #pragma unroll
    for (int it = 0; it < 2; ++it){
      int o = (it*512 + tid) * 16;
      gl2lds16(src + o, sWb + o);
    }
  }
  __syncthreads();

  for (int ev = 0; ev < 7; ++ev){
    const bool isT = !(ev & 1);
    const int  evp = ev & 1;          // sW parity generator: par(L) = (L&1) ? evp^1 : evp
    const int  term = isT ? rt : lt;
    const float* W0p = (isT ? rW0 : lW0) + term*128;
    const float* b0p = (isT ? rb0 : lb0) + term*128;
    const float* bhp = (isT ? rbh : lbh) + term*NLAYER*128;
    const float* Wop = (isT ? rWo : lWo) + term*128;
    const unsigned char* wimg = wbf + (size_t)(((isT ? 2 : 0) + term)*NLAYER)*IMGB;
    const int tnx = (ev & 1) ? rt : lt;
    const unsigned char* wimg_nx = wbf + (size_t)((((ev & 1) ? 2 : 0) + tnx)*NLAYER)*IMGB;

    // ---- input layer DIRECTLY in registers: lane (m0,q) computes element
    // le's features [32q, 32q+32) = exactly its own L=0 B-fragments. No LDS,
    // no barrier. Both ih waves duplicate (cheaper than an LDS exchange).
    int8v b0, b1;
    {
      const float x = isT ? pv : qv;
      const float2v xv = {x, x};
      const float* Wq = W0p + q*32;
      const float* Bq = b0p + q*32;
      unsigned hwv[8], dwv[8];
      #pragma unroll
      for (int j = 0; j < 8; ++j){
        float4v wv4 = *(const float4v*)(Wq + j*4);
        float4v bb4 = *(const float4v*)(Bq + j*4);
        float2v zlo = pk_fma(xv, lo2(wv4), lo2(bb4));
        float2v zhi = pk_fma(xv, hi2(wv4), hi2(bb4));
        float2v Pl, gl, Ph, gh;
        act2(zlo, Pl, gl);
        act2(zhi, Ph, gh);
        float2v hl = zlo * Pl, hh = zhi * Ph;
        float2v dl = gl * lo2(wv4), dh = gh * hi2(wv4);
        hwv[j] = pk4fp8(hl[0], hl[1], hh[0], hh[1]);
        dwv[j] = pk4fp8(dl[0], dl[1], dh[0], dh[1]);
      }
      b0 = (int8v){(int)hwv[0],(int)hwv[1],(int)hwv[2],(int)hwv[3],
                   (int)hwv[4],(int)hwv[5],(int)hwv[6],(int)hwv[7]};
      b1 = (int8v){(int)dwv[0],(int)dwv[1],(int)dwv[2],(int)dwv[3],
                   (int)dwv[4],(int)dwv[5],(int)dwv[6],(int)dwv[7]};
    }

    float2v sv = {0.f, 0.f};

    // ---- hidden layers: ping-pong sH, ONE barrier per layer ----
    #pragma unroll
    for (int L = 0; L < NLAYER; ++L){
      const int rdo = (L & 1) * 16384;      // sH read parity (compile-time)
      const int wro = rdo ^ 16384;          // sH write parity
      const int par = (L & 1) ? (evp ^ 1) : evp;   // sW read buffer (uniform)
      const int bufo = par ? IMGB : 0;
      const bool last = (L == NLAYER-1);

      // bias (and Wo at last layer) FIRST: oldest vmem, epilogue's wait leaves
      // the younger staging DMAs in flight.
      const float* bias = bhp + L*128 + ih*64 + q4;
      float4v bv0 = *(const float4v*)(bias);
      float4v bv1 = *(const float4v*)(bias + 16);
      float4v bv2 = *(const float4v*)(bias + 32);
      float4v bv3 = *(const float4v*)(bias + 48);
      float4v wo0, wo1, wo2, wo3;
      if (last){
        const float* wop = Wop + ih*64 + q4;
        wo0 = *(const float4v*)(wop);
        wo1 = *(const float4v*)(wop + 16);
        wo2 = *(const float4v*)(wop + 32);
        wo3 = *(const float4v*)(wop + 48);
      }

      // stage NEXT weight image into the other sW buffer (drains at this barrier)
      if (!(ev == 6 && L == 6)){
        const unsigned char* nsrc = (L < 6) ? (wimg + (size_t)(L+1)*IMGB) : wimg_nx;
        unsigned char* dW = sWb + (bufo ^ IMGB);
        #pragma unroll
        for (int it = 0; it < 2; ++it){
          int o = (it*512 + tid) * 16;
          gl2lds16(nsrc + o, dW + o);
        }
      }

      // B-fragments: L=0 from registers (input layer), else from sH parity
      if (L > 0){
        b0 = ld_op16(pBlo + rdo, pBhi + rdo);
        b1 = ld_op16(pBlo + rdo + 8192, pBhi + rdo + 8192);
      }

      const unsigned char* pAl = pAlo + bufo;
      const unsigned char* pAh = pAhi + bufo;
      float4v acc[4][2];
      #pragma unroll
      for (int i = 0; i < 4; ++i){
        int8v a = ld_op16(pAl + i*2048, pAh + i*2048);
        acc[i][0] = mfma128(a, b0);
        acc[i][1] = mfma128(a, b1);
      }

      // epilogue: z = acc0/256 + b; S_h' = z*P16; S_d' = gp16 * (acc1/64)
      #define EPI(i, bvv, wvv, pe) { \
        float2v za = pk_fma(lo2(acc[i][0]), inv256v, lo2(bvv)); \
        float2v zb = pk_fma(hi2(acc[i][0]), inv256v, hi2(bvv)); \
        float2v ta = lo2(acc[i][1]) * inv64v; \
        float2v tb = hi2(acc[i][1]) * inv64v; \
        float2v Pa, ga, Pb, gb; \
        act2(za, Pa, ga); \
        act2(zb, Pb, gb); \
        float2v da = ga * ta, db = gb * tb; \
        if (!last){ \
          float2v ha = za * Pa, hb = zb * Pb; \
          *(unsigned*)(pe + wro)        = pk4fp8(ha[0], ha[1], hb[0], hb[1]); \
          *(unsigned*)(pe + wro + 8192) = pk4fp8(da[0], da[1], db[0], db[1]); \
        } else { \
          sv = pk_fma(da, lo2(wvv), sv); \
          sv = pk_fma(db, hi2(wvv), sv); \
        } \
      }
      EPI(0, bv0, wo0, pE0)
      EPI(1, bv1, wo1, pE1)
      EPI(2, bv2, wo2, pE2)
      EPI(3, bv3, wo3, pE3)
      #undef EPI

      // last layer: q-reduce the ih-half partial, park in sRed (ordered by the
      // barrier below; read after it).
      if (last){
        float sh = sv[0] + sv[1];
        sh += __shfl_xor(sh, 16);
        sh += __shfl_xor(sh, 32);
        if (q == 0) sRed[ih][le] = sh;
      }

      // ONE barrier per layer: sH RAW/WAR + sW staging drain (+ sRed at L=6).
      asm volatile("s_waitcnt vmcnt(0) lgkmcnt(0)" ::: "memory");
      __builtin_amdgcn_s_barrier();
      asm volatile("" ::: "memory");
    }

    // ---- combine the two ih halves; update own element's state ----
    {
      float s = sRed[0][le] + sRed[1][le];
      if (isT) qv += coefs[ev] * s;
      else     pv += coefs[ev] * s;
    }
  }

  if (q == 0 && ih == 0){
    out[e*4 + col]     = qv;
    out[e*4 + 2 + col] = pv;
  }
}

extern "C" void kernel_launch(void* const* d_in, const int* in_sizes, int n_in,
                              void* d_out, int out_size, void* d_ws, size_t ws_size,
                              hipStream_t stream)
{
  const float* X   = (const float*)d_in[0];
  const float* lW0 = (const float*)d_in[1];
  const float* lb0 = (const float*)d_in[2];
  const float* lWh = (const float*)d_in[3];
  const float* lbh = (const float*)d_in[4];
  const float* lWo = (const float*)d_in[5];
  const float* rW0 = (const float*)d_in[7];
  const float* rb0 = (const float*)d_in[8];
  const float* rWh = (const float*)d_in[9];
  const float* rbh = (const float*)d_in[10];
  const float* rWo = (const float*)d_in[11];
  const int*   li  = (const int*)d_in[13];
  const int*   ri  = (const int*)d_in[14];
  unsigned char* wbf = (unsigned char*)d_ws;   // 4*7*16384 B = 458752 B
  float* out = (float*)d_out;
  const int B = in_sizes[0] / 4;

  hipLaunchKernelGGL(prep_weights, dim3(4*NLAYER), dim3(256), 0, stream,
                     lWh, rWh, wbf);
  hipLaunchKernelGGL(sympl_main, dim3(B/64, 2), dim3(512), 0, stream,
                     X, lW0, lb0, lbh, lWo, rW0, rb0, rbh, rWo, li, ri, wbf, out);
}